// Round 1
// baseline (352.716 us; speedup 1.0000x reference)
//
#include <hip/hip_runtime.h>
#include <hip/hip_bf16.h>

#define B_   32
#define T_   32
#define E_   32
#define SD   64
#define AD   32
#define HID  1024
#define EMB  1536
#define K2   3072   // 2*EMB

typedef __attribute__((ext_vector_type(8))) short  bf16x8;
typedef __attribute__((ext_vector_type(4))) float  f32x4;

// round-to-nearest-even f32 -> bf16 bits
__device__ __forceinline__ unsigned short f2bf(float f) {
    unsigned u = __builtin_bit_cast(unsigned, f);
    u = u + 0x7fffu + ((u >> 16) & 1u);
    return (unsigned short)(u >> 16);
}

// ---------------------------------------------------------------------------
// prep: blocks 0..31 compute tau (sinusoidal pos enc, bf16); block 32 builds
// the cat-sorted batch order (so same-cat blocks are dispatch-adjacent).
// ---------------------------------------------------------------------------
__global__ __launch_bounds__(256) void k_prep(
    const int* __restrict__ tsteps, const int* __restrict__ cat_ids,
    int* __restrict__ order, unsigned short* __restrict__ tau) {
    if (blockIdx.x == B_) {
        __shared__ int cats[B_];
        if (threadIdx.x < B_) cats[threadIdx.x] = cat_ids[threadIdx.x];
        __syncthreads();
        if (threadIdx.x == 0) {
            int idx = 0;
            for (int c = 0; c < E_; ++c)
                for (int b = 0; b < B_; ++b)
                    if (cats[b] == c) order[idx++] = b;
        }
        return;
    }
    int b = blockIdx.x;
    float t = (float)tsteps[b];
    const int half = EMB / 2;
    for (int i = threadIdx.x; i < half; i += 256) {
        float div = expf((-logf(10000.0f) * (float)i) / (float)half);
        float ang = t * div;
        tau[b * EMB + i]        = f2bf(sinf(ang));
        tau[b * EMB + half + i] = f2bf(cosf(ang));
    }
}

// ---------------------------------------------------------------------------
// state encoder layer 1: h = relu(state @ se_W1[c] + se_b1[c])   (1x64)@(64x1024)
// ---------------------------------------------------------------------------
__global__ __launch_bounds__(256) void k_state_h(
    const float* __restrict__ state, const int* __restrict__ cat_ids,
    const float* __restrict__ W1, const float* __restrict__ b1,
    float* __restrict__ h) {
    int b = blockIdx.x;
    int c = cat_ids[b];
    __shared__ float s[SD];
    if (threadIdx.x < SD) s[threadIdx.x] = state[b * SD + threadIdx.x];
    __syncthreads();
    const float* W = W1 + (size_t)c * SD * HID;
    float acc[4];
#pragma unroll
    for (int r = 0; r < 4; ++r) acc[r] = b1[c * HID + threadIdx.x + 256 * r];
    for (int k = 0; k < SD; ++k) {
        float sv = s[k];
#pragma unroll
        for (int r = 0; r < 4; ++r)
            acc[r] += sv * W[(size_t)k * HID + threadIdx.x + 256 * r];
    }
#pragma unroll
    for (int r = 0; r < 4; ++r) {
        float v = acc[r];
        h[b * HID + threadIdx.x + 256 * r] = v > 0.f ? v : 0.f;
    }
}

// ---------------------------------------------------------------------------
// state encoder layer 2: out[b,0,:] = h @ se_W2[c] + se_b2[c]   (1x1024)@(1024x1536)
// grid = 6 chunks x 32 slots, chunk-major so same-cat slots are adjacent
// ---------------------------------------------------------------------------
__global__ __launch_bounds__(256) void k_state_feat(
    const int* __restrict__ order, const int* __restrict__ cat_ids,
    const float* __restrict__ h, const float* __restrict__ W2,
    const float* __restrict__ b2, float* __restrict__ out) {
    int slot = blockIdx.x & 31, chunk = blockIdx.x >> 5;
    int b = order[slot];
    int c = cat_ids[b];
    __shared__ float sh[HID];
#pragma unroll
    for (int r = 0; r < 4; ++r)
        sh[threadIdx.x + 256 * r] = h[b * HID + threadIdx.x + 256 * r];
    __syncthreads();
    int n = chunk * 256 + threadIdx.x;
    const float* W = W2 + (size_t)c * HID * EMB + n;
    float acc = b2[c * EMB + n];
#pragma unroll 8
    for (int k = 0; k < HID; ++k)
        acc += sh[k] * W[(size_t)k * EMB];
    out[((size_t)b * 33 + 0) * EMB + n] = acc;
}

// ---------------------------------------------------------------------------
// action encoder layer 1: a_emb = actions @ ae_W1[c] + ae_b1[c] -> bf16
// (32x32)@(32x1536), K=32: k-outer, 32 row-accumulators per thread
// ---------------------------------------------------------------------------
__global__ __launch_bounds__(256) void k_aemb(
    const int* __restrict__ order, const int* __restrict__ cat_ids,
    const float* __restrict__ actions, const float* __restrict__ W1,
    const float* __restrict__ b1, unsigned short* __restrict__ aemb) {
    int slot = blockIdx.x & 31, chunk = blockIdx.x >> 5;
    int b = order[slot];
    int c = cat_ids[b];
    __shared__ float sa[T_ * AD];
#pragma unroll
    for (int r = 0; r < 4; ++r)
        sa[threadIdx.x + 256 * r] = actions[b * T_ * AD + threadIdx.x + 256 * r];
    __syncthreads();
    int n = chunk * 256 + threadIdx.x;
    const float* W = W1 + (size_t)c * AD * EMB + n;
    float bv = b1[c * EMB + n];
    float acc[T_];
#pragma unroll
    for (int t = 0; t < T_; ++t) acc[t] = bv;
    for (int k = 0; k < AD; ++k) {
        float w = W[(size_t)k * EMB];
#pragma unroll
        for (int t = 0; t < T_; ++t) acc[t] += sa[t * AD + k] * w;
    }
#pragma unroll
    for (int t = 0; t < T_; ++t)
        aemb[((size_t)b * T_ + t) * EMB + n] = f2bf(acc[t]);
}

// ---------------------------------------------------------------------------
// big GEMM 1: x3 = swish( concat([a_emb, tau]) @ ae_W2[c] + ae_b2[c] ) -> bf16
// M=32 rows (one batch), per block 64 cols, MFMA 16x16x32 bf16,
// weights f32 loaded in B-fragment order and converted in-register.
// ---------------------------------------------------------------------------
__global__ __launch_bounds__(256) void k_big1(
    const int* __restrict__ order, const int* __restrict__ cat_ids,
    const unsigned short* __restrict__ aemb, const unsigned short* __restrict__ tau,
    const float* __restrict__ W2, const float* __restrict__ b2,
    unsigned short* __restrict__ x3) {
    int slot = blockIdx.x & 31, chunk = blockIdx.x >> 5;
    int b = order[slot];
    int c = cat_ids[b];
    int tid = threadIdx.x;
    int wv = tid >> 6, lane = tid & 63;
    int col = lane & 15, kg = lane >> 4;
    int n = chunk * 64 + wv * 16 + col;

    const float* W = W2 + (size_t)c * K2 * EMB + (size_t)(kg * 8) * EMB + n;
    const unsigned short* A0 = aemb + (size_t)b * T_ * EMB;
    const unsigned short* TA = tau + (size_t)b * EMB;

    f32x4 acc0 = {0.f, 0.f, 0.f, 0.f}, acc1 = {0.f, 0.f, 0.f, 0.f};

    // region 1: k in [0,1536) -> A rows from a_emb
    for (int kk = 0; kk < EMB; kk += 32) {
        int k0 = kk + kg * 8;
        float w[8];
#pragma unroll
        for (int j = 0; j < 8; ++j) w[j] = W[(size_t)(kk + j) * EMB];
        bf16x8 bf;
#pragma unroll
        for (int j = 0; j < 8; ++j) bf[j] = (short)f2bf(w[j]);
        bf16x8 a0 = *(const bf16x8*)(A0 + (size_t)col * EMB + k0);
        bf16x8 a1 = *(const bf16x8*)(A0 + (size_t)(col + 16) * EMB + k0);
        acc0 = __builtin_amdgcn_mfma_f32_16x16x32_bf16(a0, bf, acc0, 0, 0, 0);
        acc1 = __builtin_amdgcn_mfma_f32_16x16x32_bf16(a1, bf, acc1, 0, 0, 0);
    }
    // region 2: k in [1536,3072) -> A rows are tau (same for every row)
    for (int kk = 0; kk < EMB; kk += 32) {
        int k0 = kk + kg * 8;
        float w[8];
#pragma unroll
        for (int j = 0; j < 8; ++j) w[j] = W[(size_t)(EMB + kk + j) * EMB];
        bf16x8 bf;
#pragma unroll
        for (int j = 0; j < 8; ++j) bf[j] = (short)f2bf(w[j]);
        bf16x8 a = *(const bf16x8*)(TA + k0);
        acc0 = __builtin_amdgcn_mfma_f32_16x16x32_bf16(a, bf, acc0, 0, 0, 0);
        acc1 = __builtin_amdgcn_mfma_f32_16x16x32_bf16(a, bf, acc1, 0, 0, 0);
    }

    float b2v = b2[c * EMB + n];
    int rbase = kg * 4;
#pragma unroll
    for (int r = 0; r < 4; ++r) {
        float y = acc0[r] + b2v;
        float sw = y / (1.f + expf(-y));
        x3[((size_t)b * T_ + (rbase + r)) * EMB + n] = f2bf(sw);
        y = acc1[r] + b2v;
        sw = y / (1.f + expf(-y));
        x3[((size_t)b * T_ + (rbase + r + 16)) * EMB + n] = f2bf(sw);
    }
}

// ---------------------------------------------------------------------------
// big GEMM 2: out[b,1+t,:] = x3 @ ae_W3[c] + ae_b3[c]  (f32 out)
// ---------------------------------------------------------------------------
__global__ __launch_bounds__(256) void k_big2(
    const int* __restrict__ order, const int* __restrict__ cat_ids,
    const unsigned short* __restrict__ x3, const float* __restrict__ W3,
    const float* __restrict__ b3, float* __restrict__ out) {
    int slot = blockIdx.x & 31, chunk = blockIdx.x >> 5;
    int b = order[slot];
    int c = cat_ids[b];
    int tid = threadIdx.x;
    int wv = tid >> 6, lane = tid & 63;
    int col = lane & 15, kg = lane >> 4;
    int n = chunk * 64 + wv * 16 + col;

    const float* W = W3 + (size_t)c * EMB * EMB + (size_t)(kg * 8) * EMB + n;
    const unsigned short* A0 = x3 + (size_t)b * T_ * EMB;

    f32x4 acc0 = {0.f, 0.f, 0.f, 0.f}, acc1 = {0.f, 0.f, 0.f, 0.f};

    for (int kk = 0; kk < EMB; kk += 32) {
        int k0 = kk + kg * 8;
        float w[8];
#pragma unroll
        for (int j = 0; j < 8; ++j) w[j] = W[(size_t)(kk + j) * EMB];
        bf16x8 bf;
#pragma unroll
        for (int j = 0; j < 8; ++j) bf[j] = (short)f2bf(w[j]);
        bf16x8 a0 = *(const bf16x8*)(A0 + (size_t)col * EMB + k0);
        bf16x8 a1 = *(const bf16x8*)(A0 + (size_t)(col + 16) * EMB + k0);
        acc0 = __builtin_amdgcn_mfma_f32_16x16x32_bf16(a0, bf, acc0, 0, 0, 0);
        acc1 = __builtin_amdgcn_mfma_f32_16x16x32_bf16(a1, bf, acc1, 0, 0, 0);
    }

    float b3v = b3[c * EMB + n];
    int rbase = kg * 4;
#pragma unroll
    for (int r = 0; r < 4; ++r) {
        int row0 = rbase + r;
        out[((size_t)b * 33 + 1 + row0) * EMB + n] = acc0[r] + b3v;
        out[((size_t)b * 33 + 1 + row0 + 16) * EMB + n] = acc1[r] + b3v;
    }
}

// ---------------------------------------------------------------------------
// workspace layout (bytes, 256-aligned):
//   0      : order   int[32]
//   256    : tau     bf16[32][1536]   (98304)
//   98560  : h       f32 [32][1024]   (131072)
//   229632 : a_emb   bf16[32][32][1536] (3145728)
//   3375360: x3      bf16[32][32][1536] (3145728)
//   total  : 6521088
// ---------------------------------------------------------------------------
extern "C" void kernel_launch(void* const* d_in, const int* in_sizes, int n_in,
                              void* d_out, int out_size, void* d_ws, size_t ws_size,
                              hipStream_t stream) {
    const float* state   = (const float*)d_in[0];
    const float* actions = (const float*)d_in[1];
    const int*   tsteps  = (const int*)d_in[2];
    const int*   cat_ids = (const int*)d_in[3];
    const float* se_W1 = (const float*)d_in[4];
    const float* se_b1 = (const float*)d_in[5];
    const float* se_W2 = (const float*)d_in[6];
    const float* se_b2 = (const float*)d_in[7];
    const float* ae_W1 = (const float*)d_in[8];
    const float* ae_b1 = (const float*)d_in[9];
    const float* ae_W2 = (const float*)d_in[10];
    const float* ae_b2 = (const float*)d_in[11];
    const float* ae_W3 = (const float*)d_in[12];
    const float* ae_b3 = (const float*)d_in[13];
    float* out = (float*)d_out;

    char* ws = (char*)d_ws;
    int*            order = (int*)(ws + 0);
    unsigned short* tau   = (unsigned short*)(ws + 256);
    float*          h     = (float*)(ws + 98560);
    unsigned short* aemb  = (unsigned short*)(ws + 229632);
    unsigned short* x3    = (unsigned short*)(ws + 3375360);

    k_prep<<<B_ + 1, 256, 0, stream>>>(tsteps, cat_ids, order, tau);
    k_state_h<<<B_, 256, 0, stream>>>(state, cat_ids, se_W1, se_b1, h);
    k_state_feat<<<(EMB / 256) * B_, 256, 0, stream>>>(order, cat_ids, h, se_W2, se_b2, out);
    k_aemb<<<(EMB / 256) * B_, 256, 0, stream>>>(order, cat_ids, actions, ae_W1, ae_b1, aemb);
    k_big1<<<(EMB / 64) * B_, 256, 0, stream>>>(order, cat_ids, aemb, tau, ae_W2, ae_b2, x3);
    k_big2<<<(EMB / 64) * B_, 256, 0, stream>>>(order, cat_ids, x3, ae_W3, ae_b3, out);
}

// Round 2
// 326.014 us; speedup vs baseline: 1.0819x; 1.0819x over previous
//
#include <hip/hip_runtime.h>
#include <hip/hip_bf16.h>

#define B_   32
#define T_   32
#define E_   32
#define SD   64
#define AD   32
#define HID  1024
#define EMB  1536
#define K2   3072   // 2*EMB

typedef __attribute__((ext_vector_type(8))) short  bf16x8;
typedef __attribute__((ext_vector_type(4))) float  f32x4;
typedef __attribute__((ext_vector_type(4))) short  s16x4;

// round-to-nearest-even f32 -> bf16 bits
__device__ __forceinline__ unsigned short f2bf(float f) {
    unsigned u = __builtin_bit_cast(unsigned, f);
    u = u + 0x7fffu + ((u >> 16) & 1u);
    return (unsigned short)(u >> 16);
}

// ---------------------------------------------------------------------------
// prep: blocks 0..31 compute tau (sinusoidal pos enc, bf16); block 32 builds
// the cat-sorted batch order (so same-cat blocks are dispatch-adjacent).
// ---------------------------------------------------------------------------
__global__ __launch_bounds__(256) void k_prep(
    const int* __restrict__ tsteps, const int* __restrict__ cat_ids,
    int* __restrict__ order, unsigned short* __restrict__ tau) {
    if (blockIdx.x == B_) {
        __shared__ int cats[B_];
        if (threadIdx.x < B_) cats[threadIdx.x] = cat_ids[threadIdx.x];
        __syncthreads();
        if (threadIdx.x == 0) {
            int idx = 0;
            for (int c = 0; c < E_; ++c)
                for (int b = 0; b < B_; ++b)
                    if (cats[b] == c) order[idx++] = b;
        }
        return;
    }
    int b = blockIdx.x;
    float t = (float)tsteps[b];
    const int half = EMB / 2;
    for (int i = threadIdx.x; i < half; i += 256) {
        float div = expf((-logf(10000.0f) * (float)i) / (float)half);
        float ang = t * div;
        tau[b * EMB + i]        = f2bf(sinf(ang));
        tau[b * EMB + half + i] = f2bf(cosf(ang));
    }
}

// ---------------------------------------------------------------------------
// state encoder layer 1: h = relu(state @ se_W1[c] + se_b1[c])   (1x64)@(64x1024)
// ---------------------------------------------------------------------------
__global__ __launch_bounds__(256) void k_state_h(
    const float* __restrict__ state, const int* __restrict__ cat_ids,
    const float* __restrict__ W1, const float* __restrict__ b1,
    float* __restrict__ h) {
    int b = blockIdx.x;
    int c = cat_ids[b];
    __shared__ float s[SD];
    if (threadIdx.x < SD) s[threadIdx.x] = state[b * SD + threadIdx.x];
    __syncthreads();
    const float* W = W1 + (size_t)c * SD * HID;
    float acc[4];
#pragma unroll
    for (int r = 0; r < 4; ++r) acc[r] = b1[c * HID + threadIdx.x + 256 * r];
    for (int k = 0; k < SD; ++k) {
        float sv = s[k];
#pragma unroll
        for (int r = 0; r < 4; ++r)
            acc[r] += sv * W[(size_t)k * HID + threadIdx.x + 256 * r];
    }
#pragma unroll
    for (int r = 0; r < 4; ++r) {
        float v = acc[r];
        h[b * HID + threadIdx.x + 256 * r] = v > 0.f ? v : 0.f;
    }
}

// ---------------------------------------------------------------------------
// state encoder layer 2: out[b,0,:] = h @ se_W2[c] + se_b2[c]   (1x1024)@(1024x1536)
// 1-wave blocks, each lane owns 4 consecutive cols, dwordx4 weight loads.
// grid = 6 chunks x 32 slots (slot-adjacent blocks share cat -> L3 dedup)
// ---------------------------------------------------------------------------
__global__ __launch_bounds__(64) void k_state_feat(
    const int* __restrict__ order, const int* __restrict__ cat_ids,
    const float* __restrict__ h, const float* __restrict__ W2,
    const float* __restrict__ b2, float* __restrict__ out) {
    int slot = blockIdx.x & 31, chunk = blockIdx.x >> 5;   // chunk 0..5
    int b = order[slot];
    int c = cat_ids[b];
    int lane = threadIdx.x;
    int n = chunk * 256 + 4 * lane;
    const float* W = W2 + (size_t)c * HID * EMB + n;
    const float* hb = h + (size_t)b * HID;
    f32x4 acc = *(const f32x4*)(b2 + (size_t)c * EMB + n);
#pragma unroll 16
    for (int k = 0; k < HID; ++k) {
        f32x4 wv = *(const f32x4*)(W + (size_t)k * EMB);
        float hk = hb[k];          // wave-uniform -> scalar load
        acc += hk * wv;
    }
    *(f32x4*)(out + ((size_t)b * 33 + 0) * EMB + n) = acc;
}

// ---------------------------------------------------------------------------
// action encoder layer 1: a_emb = actions @ ae_W1[c] + ae_b1[c] -> bf16
// (32x32)@(32x1536), K=32: k-outer, 32 row-accumulators per thread
// ---------------------------------------------------------------------------
__global__ __launch_bounds__(256) void k_aemb(
    const int* __restrict__ order, const int* __restrict__ cat_ids,
    const float* __restrict__ actions, const float* __restrict__ W1,
    const float* __restrict__ b1, unsigned short* __restrict__ aemb) {
    int slot = blockIdx.x & 31, chunk = blockIdx.x >> 5;
    int b = order[slot];
    int c = cat_ids[b];
    __shared__ float sa[T_ * AD];
#pragma unroll
    for (int r = 0; r < 4; ++r)
        sa[threadIdx.x + 256 * r] = actions[b * T_ * AD + threadIdx.x + 256 * r];
    __syncthreads();
    int n = chunk * 256 + threadIdx.x;
    const float* W = W1 + (size_t)c * AD * EMB + n;
    float bv = b1[c * EMB + n];
    float acc[T_];
#pragma unroll
    for (int t = 0; t < T_; ++t) acc[t] = bv;
    for (int k = 0; k < AD; ++k) {
        float w = W[(size_t)k * EMB];
#pragma unroll
        for (int t = 0; t < T_; ++t) acc[t] += sa[t * AD + k] * w;
    }
#pragma unroll
    for (int t = 0; t < T_; ++t)
        aemb[((size_t)b * T_ + t) * EMB + n] = f2bf(acc[t]);
}

// ---------------------------------------------------------------------------
// big GEMM 1: x3 = swish( concat([a_emb, tau]) @ ae_W2[c] + ae_b2[c] ) -> bf16
// 1-wave blocks. Lane loads W[k][4*(lane&15)+q..+3] as dwordx4 (fully
// contiguous 256B per 16 lanes); 4 MFMAs per (rowhalf,kk), one per column
// residue q: B-frag bq[q][j] = bf16(w[j][q]); MFMA col c maps to 4c+q.
// ---------------------------------------------------------------------------
__global__ __launch_bounds__(64) void k_big1(
    const int* __restrict__ order, const int* __restrict__ cat_ids,
    const unsigned short* __restrict__ aemb, const unsigned short* __restrict__ tau,
    const float* __restrict__ W2, const float* __restrict__ b2,
    unsigned short* __restrict__ x3) {
    int slot = blockIdx.x & 31, chunk = blockIdx.x >> 5;   // chunk 0..23
    int b = order[slot];
    int c = cat_ids[b];
    int lane = threadIdx.x;
    int cq = lane & 15;        // col-quad index (= MFMA col)
    int kg = lane >> 4;        // k-group 0..3
    int ncol = chunk * 64 + 4 * cq;

    const float* Wbase = W2 + (size_t)c * K2 * EMB + ncol;
    const unsigned short* A0 = aemb + (size_t)b * T_ * EMB;
    const unsigned short* TA = tau + (size_t)b * EMB;

    f32x4 acc[2][4];
#pragma unroll
    for (int rf = 0; rf < 2; ++rf)
#pragma unroll
        for (int q = 0; q < 4; ++q) acc[rf][q] = (f32x4){0.f, 0.f, 0.f, 0.f};

    // region 1: k in [0,1536), A rows from a_emb
#pragma unroll 2
    for (int kk = 0; kk < EMB; kk += 32) {
        int kbase = kk + kg * 8;
        f32x4 w[8];
#pragma unroll
        for (int j = 0; j < 8; ++j)
            w[j] = *(const f32x4*)(Wbase + (size_t)(kbase + j) * EMB);
        bf16x8 bq[4];
#pragma unroll
        for (int q = 0; q < 4; ++q) {
#pragma unroll
            for (int j = 0; j < 8; ++j) bq[q][j] = (short)f2bf(w[j][q]);
        }
        bf16x8 a0 = *(const bf16x8*)(A0 + (size_t)cq * EMB + kbase);
        bf16x8 a1 = *(const bf16x8*)(A0 + (size_t)(cq + 16) * EMB + kbase);
#pragma unroll
        for (int q = 0; q < 4; ++q) {
            acc[0][q] = __builtin_amdgcn_mfma_f32_16x16x32_bf16(a0, bq[q], acc[0][q], 0, 0, 0);
            acc[1][q] = __builtin_amdgcn_mfma_f32_16x16x32_bf16(a1, bq[q], acc[1][q], 0, 0, 0);
        }
    }
    // region 2: k in [1536,3072), A rows all equal tau
#pragma unroll 2
    for (int kk = 0; kk < EMB; kk += 32) {
        int kbase = kk + kg * 8;
        f32x4 w[8];
#pragma unroll
        for (int j = 0; j < 8; ++j)
            w[j] = *(const f32x4*)(Wbase + (size_t)(EMB + kbase + j) * EMB);
        bf16x8 bq[4];
#pragma unroll
        for (int q = 0; q < 4; ++q) {
#pragma unroll
            for (int j = 0; j < 8; ++j) bq[q][j] = (short)f2bf(w[j][q]);
        }
        bf16x8 a = *(const bf16x8*)(TA + kbase);
#pragma unroll
        for (int q = 0; q < 4; ++q) {
            acc[0][q] = __builtin_amdgcn_mfma_f32_16x16x32_bf16(a, bq[q], acc[0][q], 0, 0, 0);
            acc[1][q] = __builtin_amdgcn_mfma_f32_16x16x32_bf16(a, bq[q], acc[1][q], 0, 0, 0);
        }
    }

    f32x4 bias = *(const f32x4*)(b2 + (size_t)c * EMB + ncol);
#pragma unroll
    for (int rf = 0; rf < 2; ++rf) {
#pragma unroll
        for (int r = 0; r < 4; ++r) {
            int row = kg * 4 + r + 16 * rf;   // C/D: row=(lane>>4)*4+reg
            s16x4 o;
#pragma unroll
            for (int q = 0; q < 4; ++q) {
                float y = acc[rf][q][r] + bias[q];
                float sw = y / (1.f + expf(-y));
                o[q] = (short)f2bf(sw);
            }
            *(s16x4*)(x3 + ((size_t)b * T_ + row) * EMB + ncol) = o;
        }
    }
}

// ---------------------------------------------------------------------------
// big GEMM 2: out[b,1+t,:] = x3 @ ae_W3[c] + ae_b3[c]  (f32 out, float4 stores)
// ---------------------------------------------------------------------------
__global__ __launch_bounds__(64) void k_big2(
    const int* __restrict__ order, const int* __restrict__ cat_ids,
    const unsigned short* __restrict__ x3, const float* __restrict__ W3,
    const float* __restrict__ b3, float* __restrict__ out) {
    int slot = blockIdx.x & 31, chunk = blockIdx.x >> 5;   // chunk 0..23
    int b = order[slot];
    int c = cat_ids[b];
    int lane = threadIdx.x;
    int cq = lane & 15;
    int kg = lane >> 4;
    int ncol = chunk * 64 + 4 * cq;

    const float* Wbase = W3 + (size_t)c * EMB * EMB + ncol;
    const unsigned short* A0 = x3 + (size_t)b * T_ * EMB;

    f32x4 acc[2][4];
#pragma unroll
    for (int rf = 0; rf < 2; ++rf)
#pragma unroll
        for (int q = 0; q < 4; ++q) acc[rf][q] = (f32x4){0.f, 0.f, 0.f, 0.f};

#pragma unroll 2
    for (int kk = 0; kk < EMB; kk += 32) {
        int kbase = kk + kg * 8;
        f32x4 w[8];
#pragma unroll
        for (int j = 0; j < 8; ++j)
            w[j] = *(const f32x4*)(Wbase + (size_t)(kbase + j) * EMB);
        bf16x8 bq[4];
#pragma unroll
        for (int q = 0; q < 4; ++q) {
#pragma unroll
            for (int j = 0; j < 8; ++j) bq[q][j] = (short)f2bf(w[j][q]);
        }
        bf16x8 a0 = *(const bf16x8*)(A0 + (size_t)cq * EMB + kbase);
        bf16x8 a1 = *(const bf16x8*)(A0 + (size_t)(cq + 16) * EMB + kbase);
#pragma unroll
        for (int q = 0; q < 4; ++q) {
            acc[0][q] = __builtin_amdgcn_mfma_f32_16x16x32_bf16(a0, bq[q], acc[0][q], 0, 0, 0);
            acc[1][q] = __builtin_amdgcn_mfma_f32_16x16x32_bf16(a1, bq[q], acc[1][q], 0, 0, 0);
        }
    }

    f32x4 bias = *(const f32x4*)(b3 + (size_t)c * EMB + ncol);
#pragma unroll
    for (int rf = 0; rf < 2; ++rf) {
#pragma unroll
        for (int r = 0; r < 4; ++r) {
            int row = kg * 4 + r + 16 * rf;
            f32x4 ov;
#pragma unroll
            for (int q = 0; q < 4; ++q) ov[q] = acc[rf][q][r] + bias[q];
            *(f32x4*)(out + ((size_t)b * 33 + 1 + row) * EMB + ncol) = ov;
        }
    }
}

// ---------------------------------------------------------------------------
// workspace layout (bytes, 256-aligned):
//   0      : order   int[32]
//   256    : tau     bf16[32][1536]   (98304)
//   98560  : h       f32 [32][1024]   (131072)
//   229632 : a_emb   bf16[32][32][1536] (3145728)
//   3375360: x3      bf16[32][32][1536] (3145728)
//   total  : 6521088
// ---------------------------------------------------------------------------
extern "C" void kernel_launch(void* const* d_in, const int* in_sizes, int n_in,
                              void* d_out, int out_size, void* d_ws, size_t ws_size,
                              hipStream_t stream) {
    const float* state   = (const float*)d_in[0];
    const float* actions = (const float*)d_in[1];
    const int*   tsteps  = (const int*)d_in[2];
    const int*   cat_ids = (const int*)d_in[3];
    const float* se_W1 = (const float*)d_in[4];
    const float* se_b1 = (const float*)d_in[5];
    const float* se_W2 = (const float*)d_in[6];
    const float* se_b2 = (const float*)d_in[7];
    const float* ae_W1 = (const float*)d_in[8];
    const float* ae_b1 = (const float*)d_in[9];
    const float* ae_W2 = (const float*)d_in[10];
    const float* ae_b2 = (const float*)d_in[11];
    const float* ae_W3 = (const float*)d_in[12];
    const float* ae_b3 = (const float*)d_in[13];
    float* out = (float*)d_out;

    char* ws = (char*)d_ws;
    int*            order = (int*)(ws + 0);
    unsigned short* tau   = (unsigned short*)(ws + 256);
    float*          h     = (float*)(ws + 98560);
    unsigned short* aemb  = (unsigned short*)(ws + 229632);
    unsigned short* x3    = (unsigned short*)(ws + 3375360);

    k_prep<<<B_ + 1, 256, 0, stream>>>(tsteps, cat_ids, order, tau);
    k_state_h<<<B_, 256, 0, stream>>>(state, cat_ids, se_W1, se_b1, h);
    k_state_feat<<<(EMB / 256) * B_, 64, 0, stream>>>(order, cat_ids, h, se_W2, se_b2, out);
    k_aemb<<<(EMB / 256) * B_, 256, 0, stream>>>(order, cat_ids, actions, ae_W1, ae_b1, aemb);
    k_big1<<<(EMB / 64) * B_, 64, 0, stream>>>(order, cat_ids, aemb, tau, ae_W2, ae_b2, x3);
    k_big2<<<(EMB / 64) * B_, 64, 0, stream>>>(order, cat_ids, x3, ae_W3, ae_b3, out);
}

// Round 3
// 214.380 us; speedup vs baseline: 1.6453x; 1.5207x over previous
//
#include <hip/hip_runtime.h>
#include <hip/hip_bf16.h>

#define B_   32
#define T_   32
#define E_   32
#define SD   64
#define AD   32
#define HID  1024
#define EMB  1536
#define K2   3072   // 2*EMB

typedef __attribute__((ext_vector_type(8))) short  bf16x8;
typedef __attribute__((ext_vector_type(8))) short  s16x8;
typedef __attribute__((ext_vector_type(4))) float  f32x4;

// round-to-nearest-even f32 -> bf16 bits
__device__ __forceinline__ unsigned short f2bf(float f) {
    unsigned u = __builtin_bit_cast(unsigned, f);
    u = u + 0x7fffu + ((u >> 16) & 1u);
    return (unsigned short)(u >> 16);
}

__device__ __forceinline__ float swishf(float y) {
    return y / (1.f + expf(-y));
}

// ---------------------------------------------------------------------------
// k0: fused independent prep work.
//   block 0        : cat-sorted batch order (serial, trivial)
//   blocks 1..32   : tau sinusoid table (bf16) for batch bid-1
//   blocks 33..64  : state encoder layer 1 (relu(state@se_W1+b1)) for bid-33
//   blocks 65..256 : a_emb = actions @ ae_W1 + b1 -> bf16  (192 blocks)
// ---------------------------------------------------------------------------
__global__ __launch_bounds__(256) void k0(
    const float* __restrict__ state, const float* __restrict__ actions,
    const int* __restrict__ tsteps, const int* __restrict__ cat_ids,
    const float* __restrict__ se_W1, const float* __restrict__ se_b1,
    const float* __restrict__ ae_W1, const float* __restrict__ ae_b1,
    int* __restrict__ order, unsigned short* __restrict__ tau,
    float* __restrict__ h, unsigned short* __restrict__ aemb) {
    int bid = blockIdx.x, tid = threadIdx.x;

    if (bid == 0) {                         // ---- order sort
        __shared__ int cats[B_];
        if (tid < B_) cats[tid] = cat_ids[tid];
        __syncthreads();
        if (tid == 0) {
            int idx = 0;
            for (int c = 0; c < E_; ++c)
                for (int b = 0; b < B_; ++b)
                    if (cats[b] == c) order[idx++] = b;
        }
        return;
    }
    if (bid <= B_) {                        // ---- tau
        int b = bid - 1;
        float t = (float)tsteps[b];
        const int half = EMB / 2;
        for (int i = tid; i < half; i += 256) {
            float div = expf((-logf(10000.0f) * (float)i) / (float)half);
            float ang = t * div;
            tau[b * EMB + i]        = f2bf(sinf(ang));
            tau[b * EMB + half + i] = f2bf(cosf(ang));
        }
        return;
    }
    if (bid <= 2 * B_) {                    // ---- state_h
        int b = bid - (B_ + 1);
        int c = cat_ids[b];
        __shared__ float s[SD];
        if (tid < SD) s[tid] = state[b * SD + tid];
        __syncthreads();
        const float* W = se_W1 + (size_t)c * SD * HID;
        float acc[4];
#pragma unroll
        for (int r = 0; r < 4; ++r) acc[r] = se_b1[c * HID + tid + 256 * r];
        for (int k = 0; k < SD; ++k) {
            float sv = s[k];
#pragma unroll
            for (int r = 0; r < 4; ++r)
                acc[r] += sv * W[(size_t)k * HID + tid + 256 * r];
        }
#pragma unroll
        for (int r = 0; r < 4; ++r) {
            float v = acc[r];
            h[b * HID + tid + 256 * r] = v > 0.f ? v : 0.f;
        }
        return;
    }
    // ---- aemb: (32x32)@(32x1536)
    {
        int idx = bid - (2 * B_ + 1);       // 0..191
        int b = idx & 31, chunk = idx >> 5;
        int c = cat_ids[b];
        __shared__ float sa[T_ * AD];
#pragma unroll
        for (int r = 0; r < 4; ++r)
            sa[tid + 256 * r] = actions[b * T_ * AD + tid + 256 * r];
        __syncthreads();
        int n = chunk * 256 + tid;
        const float* W = ae_W1 + (size_t)c * AD * EMB + n;
        float bv = ae_b1[c * EMB + n];
        float acc[T_];
#pragma unroll
        for (int t = 0; t < T_; ++t) acc[t] = bv;
        for (int k = 0; k < AD; ++k) {
            float w = W[(size_t)k * EMB];
#pragma unroll
            for (int t = 0; t < T_; ++t) acc[t] += sa[t * AD + k] * w;
        }
#pragma unroll
        for (int t = 0; t < T_; ++t)
            aemb[((size_t)b * T_ + t) * EMB + n] = f2bf(acc[t]);
    }
}

// ---------------------------------------------------------------------------
// k1: blocks 0..767  = big GEMM 1 (x3 = swish(concat(a_emb,tau)@ae_W2+b2))
//     blocks 768..959 = state_feat (out row0 = h@se_W2+b2)
// Both: 4-wave K-split + LDS reduce. big1: wave w owns k in [768w,768w+768)
// (waves 0,1 -> a_emb region; waves 2,3 -> tau region). Lane loads
// W[k][4*(lane&15)+q..+3] as dwordx4; 4 MFMAs per (rowhalf,k-step), one per
// column residue q; MFMA col c maps to global col 4c+q.
// ---------------------------------------------------------------------------
__global__ __launch_bounds__(256) void k1(
    const int* __restrict__ order, const int* __restrict__ cat_ids,
    const unsigned short* __restrict__ aemb, const unsigned short* __restrict__ tau,
    const float* __restrict__ ae_W2, const float* __restrict__ ae_b2,
    const float* __restrict__ h, const float* __restrict__ se_W2,
    const float* __restrict__ se_b2,
    unsigned short* __restrict__ x3, float* __restrict__ out) {
    __shared__ float lds[4][32][64];        // 32 KB partial staging
    int bid = blockIdx.x, tid = threadIdx.x;
    int wv = tid >> 6, lane = tid & 63;

    if (bid < (EMB / 64) * B_) {            // ---- big1 (768 blocks)
        int slot = bid & 31, chunk = bid >> 5;
        int b = order[slot];
        int c = cat_ids[b];
        int cq = lane & 15, kg = lane >> 4;
        int ncol = chunk * 64 + 4 * cq;
        const float* Wb = ae_W2 + (size_t)c * K2 * EMB + ncol;

        f32x4 acc[2][4];
#pragma unroll
        for (int rf = 0; rf < 2; ++rf)
#pragma unroll
            for (int q = 0; q < 4; ++q) acc[rf][q] = (f32x4){0.f, 0.f, 0.f, 0.f};

        int kbeg = wv * 768;
        if (wv < 2) {                       // a_emb region (k 0..1535)
            const unsigned short* A0 = aemb + (size_t)b * T_ * EMB;
#pragma unroll 2
            for (int kk = 0; kk < 768; kk += 32) {
                int kb = kbeg + kk + kg * 8;
                f32x4 w[8];
#pragma unroll
                for (int j = 0; j < 8; ++j)
                    w[j] = *(const f32x4*)(Wb + (size_t)(kb + j) * EMB);
                bf16x8 bq[4];
#pragma unroll
                for (int q = 0; q < 4; ++q)
#pragma unroll
                    for (int j = 0; j < 8; ++j) bq[q][j] = (short)f2bf(w[j][q]);
                bf16x8 a0 = *(const bf16x8*)(A0 + (size_t)cq * EMB + kb);
                bf16x8 a1 = *(const bf16x8*)(A0 + (size_t)(cq + 16) * EMB + kb);
#pragma unroll
                for (int q = 0; q < 4; ++q) {
                    acc[0][q] = __builtin_amdgcn_mfma_f32_16x16x32_bf16(a0, bq[q], acc[0][q], 0, 0, 0);
                    acc[1][q] = __builtin_amdgcn_mfma_f32_16x16x32_bf16(a1, bq[q], acc[1][q], 0, 0, 0);
                }
            }
        } else {                            // tau region (k 1536..3071), rows equal
            const unsigned short* TA = tau + (size_t)b * EMB;
#pragma unroll 2
            for (int kk = 0; kk < 768; kk += 32) {
                int kb = kbeg + kk + kg * 8;
                f32x4 w[8];
#pragma unroll
                for (int j = 0; j < 8; ++j)
                    w[j] = *(const f32x4*)(Wb + (size_t)(kb + j) * EMB);
                bf16x8 bq[4];
#pragma unroll
                for (int q = 0; q < 4; ++q)
#pragma unroll
                    for (int j = 0; j < 8; ++j) bq[q][j] = (short)f2bf(w[j][q]);
                bf16x8 a = *(const bf16x8*)(TA + (kb - EMB));
#pragma unroll
                for (int q = 0; q < 4; ++q) {
                    acc[0][q] = __builtin_amdgcn_mfma_f32_16x16x32_bf16(a, bq[q], acc[0][q], 0, 0, 0);
                    acc[1][q] = __builtin_amdgcn_mfma_f32_16x16x32_bf16(a, bq[q], acc[1][q], 0, 0, 0);
                }
            }
        }
        // stage partials: C/D layout row=(lane>>4)*4+reg+16*rf, col=4*cq+q
#pragma unroll
        for (int rf = 0; rf < 2; ++rf)
#pragma unroll
            for (int r = 0; r < 4; ++r) {
                int row = kg * 4 + r + 16 * rf;
                f32x4 v;
#pragma unroll
                for (int q = 0; q < 4; ++q) v[q] = acc[rf][q][r];
                *(f32x4*)&lds[wv][row][4 * cq] = v;
            }
        __syncthreads();
        // epilogue: thread -> (row=tid>>3, cols 8*(tid&7)..+7)
        int row = tid >> 3, c0 = (tid & 7) * 8;
        int gcol = chunk * 64 + c0;
        s16x8 o;
#pragma unroll
        for (int j = 0; j < 8; ++j) {
            float y = lds[0][row][c0 + j] + lds[1][row][c0 + j]
                    + lds[2][row][c0 + j] + lds[3][row][c0 + j]
                    + ae_b2[c * EMB + gcol + j];
            o[j] = (short)f2bf(swishf(y));
        }
        *(s16x8*)(x3 + ((size_t)b * T_ + row) * EMB + gcol) = o;
    } else {                                // ---- state_feat (192 blocks)
        int idx = bid - (EMB / 64) * B_;
        int slot = idx & 31, chunk = idx >> 5;
        int b = order[slot];
        int c = cat_ids[b];
        int n = chunk * 256 + 4 * lane;
        const float* W = se_W2 + (size_t)c * HID * EMB + n;
        const float* hb = h + (size_t)b * HID;
        f32x4 acc = {0.f, 0.f, 0.f, 0.f};
        int ke = 256 * wv + 256;
#pragma unroll 16
        for (int k = 256 * wv; k < ke; ++k) {
            f32x4 wvv = *(const f32x4*)(W + (size_t)k * EMB);
            float hk = hb[k];
            acc += hk * wvv;
        }
        float* l = (float*)lds;
        *(f32x4*)&l[(wv * 64 + lane) * 4] = acc;
        __syncthreads();
        if (tid < 64) {
            f32x4 s = *(f32x4*)&l[tid * 4];
#pragma unroll
            for (int w = 1; w < 4; ++w) s += *(f32x4*)&l[(w * 64 + tid) * 4];
            s += *(const f32x4*)(se_b2 + (size_t)c * EMB + chunk * 256 + 4 * tid);
            *(f32x4*)(out + ((size_t)b * 33) * EMB + chunk * 256 + 4 * tid) = s;
        }
    }
}

// ---------------------------------------------------------------------------
// k2: big GEMM 2: out[b,1+t,:] = x3 @ ae_W3[c] + ae_b3[c]
// 4-wave K-split (384 each) + LDS reduce, f32x4 stores.
// ---------------------------------------------------------------------------
__global__ __launch_bounds__(256) void k2(
    const int* __restrict__ order, const int* __restrict__ cat_ids,
    const unsigned short* __restrict__ x3, const float* __restrict__ ae_W3,
    const float* __restrict__ ae_b3, float* __restrict__ out) {
    __shared__ float lds[4][32][64];
    int bid = blockIdx.x, tid = threadIdx.x;
    int wv = tid >> 6, lane = tid & 63;
    int slot = bid & 31, chunk = bid >> 5;
    int b = order[slot];
    int c = cat_ids[b];
    int cq = lane & 15, kg = lane >> 4;
    int ncol = chunk * 64 + 4 * cq;
    const float* Wb = ae_W3 + (size_t)c * EMB * EMB + ncol;
    const unsigned short* A0 = x3 + (size_t)b * T_ * EMB;

    f32x4 acc[2][4];
#pragma unroll
    for (int rf = 0; rf < 2; ++rf)
#pragma unroll
        for (int q = 0; q < 4; ++q) acc[rf][q] = (f32x4){0.f, 0.f, 0.f, 0.f};

    int kbeg = wv * 384;
#pragma unroll 2
    for (int kk = 0; kk < 384; kk += 32) {
        int kb = kbeg + kk + kg * 8;
        f32x4 w[8];
#pragma unroll
        for (int j = 0; j < 8; ++j)
            w[j] = *(const f32x4*)(Wb + (size_t)(kb + j) * EMB);
        bf16x8 bq[4];
#pragma unroll
        for (int q = 0; q < 4; ++q)
#pragma unroll
            for (int j = 0; j < 8; ++j) bq[q][j] = (short)f2bf(w[j][q]);
        bf16x8 a0 = *(const bf16x8*)(A0 + (size_t)cq * EMB + kb);
        bf16x8 a1 = *(const bf16x8*)(A0 + (size_t)(cq + 16) * EMB + kb);
#pragma unroll
        for (int q = 0; q < 4; ++q) {
            acc[0][q] = __builtin_amdgcn_mfma_f32_16x16x32_bf16(a0, bq[q], acc[0][q], 0, 0, 0);
            acc[1][q] = __builtin_amdgcn_mfma_f32_16x16x32_bf16(a1, bq[q], acc[1][q], 0, 0, 0);
        }
    }
#pragma unroll
    for (int rf = 0; rf < 2; ++rf)
#pragma unroll
        for (int r = 0; r < 4; ++r) {
            int row = kg * 4 + r + 16 * rf;
            f32x4 v;
#pragma unroll
            for (int q = 0; q < 4; ++q) v[q] = acc[rf][q][r];
            *(f32x4*)&lds[wv][row][4 * cq] = v;
        }
    __syncthreads();
    int row = tid >> 3, c0 = (tid & 7) * 8;
    int gcol = chunk * 64 + c0;
    f32x4 o0, o1;
#pragma unroll
    for (int j = 0; j < 4; ++j) {
        o0[j] = lds[0][row][c0 + j] + lds[1][row][c0 + j]
              + lds[2][row][c0 + j] + lds[3][row][c0 + j]
              + ae_b3[c * EMB + gcol + j];
        o1[j] = lds[0][row][c0 + 4 + j] + lds[1][row][c0 + 4 + j]
              + lds[2][row][c0 + 4 + j] + lds[3][row][c0 + 4 + j]
              + ae_b3[c * EMB + gcol + 4 + j];
    }
    float* orow = out + ((size_t)b * 33 + 1 + row) * EMB + gcol;
    *(f32x4*)orow = o0;
    *(f32x4*)(orow + 4) = o1;
}

// ---------------------------------------------------------------------------
// workspace layout (bytes, 256-aligned):
//   0      : order   int[32]
//   256    : tau     bf16[32][1536]   (98304)
//   98560  : h       f32 [32][1024]   (131072)
//   229632 : a_emb   bf16[32][32][1536] (3145728)
//   3375360: x3      bf16[32][32][1536] (3145728)
//   total  : 6521088
// ---------------------------------------------------------------------------
extern "C" void kernel_launch(void* const* d_in, const int* in_sizes, int n_in,
                              void* d_out, int out_size, void* d_ws, size_t ws_size,
                              hipStream_t stream) {
    const float* state   = (const float*)d_in[0];
    const float* actions = (const float*)d_in[1];
    const int*   tsteps  = (const int*)d_in[2];
    const int*   cat_ids = (const int*)d_in[3];
    const float* se_W1 = (const float*)d_in[4];
    const float* se_b1 = (const float*)d_in[5];
    const float* se_W2 = (const float*)d_in[6];
    const float* se_b2 = (const float*)d_in[7];
    const float* ae_W1 = (const float*)d_in[8];
    const float* ae_b1 = (const float*)d_in[9];
    const float* ae_W2 = (const float*)d_in[10];
    const float* ae_b2 = (const float*)d_in[11];
    const float* ae_W3 = (const float*)d_in[12];
    const float* ae_b3 = (const float*)d_in[13];
    float* out = (float*)d_out;

    char* ws = (char*)d_ws;
    int*            order = (int*)(ws + 0);
    unsigned short* tau   = (unsigned short*)(ws + 256);
    float*          h     = (float*)(ws + 98560);
    unsigned short* aemb  = (unsigned short*)(ws + 229632);
    unsigned short* x3    = (unsigned short*)(ws + 3375360);

    k0<<<1 + 2 * B_ + (EMB / 256) * B_, 256, 0, stream>>>(
        state, actions, tsteps, cat_ids, se_W1, se_b1, ae_W1, ae_b1,
        order, tau, h, aemb);
    k1<<<(EMB / 64) * B_ + (EMB / 256) * B_, 256, 0, stream>>>(
        order, cat_ids, aemb, tau, ae_W2, ae_b2, h, se_W2, se_b2, x3, out);
    k2<<<(EMB / 64) * B_, 256, 0, stream>>>(order, cat_ids, x3, ae_W3, ae_b3, out);
}